// Round 7
// baseline (757.364 us; speedup 1.0000x reference)
//
#include <hip/hip_runtime.h>
#include <hip/hip_bf16.h>

#define N_NODES 50000
#define E_EDGES 200000
static constexpr float INV_SQRT_C = 0.08838834764831845f; // 1/sqrt(128)

typedef __attribute__((ext_vector_type(4))) float f32x4;
typedef __attribute__((ext_vector_type(8))) short s16x8;
typedef __attribute__((ext_vector_type(4))) short s16x4;

__device__ __forceinline__ float b2f(unsigned short u) {
  union { unsigned u; float f; } x; x.u = ((unsigned)u) << 16; return x.f;
}
__device__ __forceinline__ short f2b(float f) {
  union { float f; unsigned u; } x; x.f = f;
  unsigned r = x.u + 0x7FFFu + ((x.u >> 16) & 1u);  // RNE
  return (short)(r >> 16);
}

struct WPtrs { const float* w[10]; };

// Repack 10 [256x256] f32 weights into bf16 MFMA-fragment order:
//   out[((ct*8 + ks)*16 + colb)*32 + g*8 + j] = W[ks*32 + g*8 + j][ct*16 + colb]
__global__ __launch_bounds__(256) void prep_transpose(WPtrs p, short* __restrict__ out) {
  __shared__ short T[256 * 66];
  const int wi = blockIdx.x >> 2, cq = blockIdx.x & 3;
  const float* w = p.w[wi];
  short* o = out + wi * 65536;
  const int tid = threadIdx.x;
#pragma unroll
  for (int i = 0; i < 64; ++i) {
    int flat = tid + i * 256;
    int k = flat >> 6, cc = flat & 63;
    T[k * 66 + cc] = f2b(w[k * 256 + cq * 64 + cc]);
  }
  __syncthreads();
#pragma unroll
  for (int i = 0; i < 8; ++i) {
    int flat2 = tid + i * 256;
    int g = flat2 & 3, colb = (flat2 >> 2) & 15, ks = (flat2 >> 6) & 7, ctl = flat2 >> 9;
    int ct = cq * 4 + ctl;
    s16x8 v;
#pragma unroll
    for (int j = 0; j < 8; ++j)
      v[j] = T[(ks * 32 + g * 8 + j) * 66 + ctl * 16 + colb];
    *(s16x8*)(o + (((ct * 8 + ks) * 16 + colb) * 32 + g * 8)) = v;
  }
}

// ---------------- node GEMM v5 ----------------
// 512 thr / 8 waves, 64 rows/block, wave owns 32 cols (2 ct), 2 jobs.
// Both jobs' MFMAs run first (As stays live), then each job's result is
// bounced through the As LDS buffer for fully-coalesced global stores
// (the old 2B-scattered epilogue was the kernel's bottleneck).
__global__ __launch_bounds__(512) void node_gemm5(
    const float* __restrict__ X, int M,
    const short* __restrict__ Wt0, const float* __restrict__ bias0,
    unsigned short* __restrict__ o16_0, float* __restrict__ of0,
    const short* __restrict__ Wt1, const float* __restrict__ bias1,
    unsigned short* __restrict__ o16_1, float* __restrict__ of1)
{
  __shared__ __align__(16) char smem[67584];   // As 64x264 bf16 / epilogue buffer
  short* As = (short*)smem;
  const int tid = threadIdx.x;
  const int l = tid & 63;
  const int w = tid >> 6;
  const int m0 = blockIdx.x * 64;
  const bool fullblk = (m0 + 64 <= M);

  if (fullblk) {
#pragma unroll
    for (int i = 0; i < 8; ++i) {
      int flat = tid + i * 512;
      int r = flat >> 6, c4 = flat & 63;
      float4 xv = *(const float4*)(X + (size_t)(m0 + r) * 256 + c4 * 4);
      s16x4 sv; sv[0] = f2b(xv.x); sv[1] = f2b(xv.y); sv[2] = f2b(xv.z); sv[3] = f2b(xv.w);
      *(s16x4*)&As[r * 264 + c4 * 4] = sv;
    }
  } else {
#pragma unroll
    for (int i = 0; i < 8; ++i) {
      int flat = tid + i * 512;
      int r = flat >> 6, c4 = flat & 63;
      float4 xv = make_float4(0.f, 0.f, 0.f, 0.f);
      if (m0 + r < M) xv = *(const float4*)(X + (size_t)(m0 + r) * 256 + c4 * 4);
      s16x4 sv; sv[0] = f2b(xv.x); sv[1] = f2b(xv.y); sv[2] = f2b(xv.z); sv[3] = f2b(xv.w);
      *(s16x4*)&As[r * 264 + c4 * 4] = sv;
    }
  }
  __syncthreads();

  const int colb = l & 15;
  const int g = l >> 4;

  // ---- MFMA for both jobs (As must stay live) ----
  f32x4 acc[2][4][2];
#pragma unroll
  for (int job = 0; job < 2; ++job) {
    const short* Wt = job ? Wt1 : Wt0;
    const short* wbase0 = Wt + (((2 * w + 0) * 8) * 16 + colb) * 32 + g * 8;
    const short* wbase1 = Wt + (((2 * w + 1) * 8) * 16 + colb) * 32 + g * 8;
#pragma unroll
    for (int m = 0; m < 4; ++m) { acc[job][m][0] = (f32x4)(0.0f); acc[job][m][1] = (f32x4)(0.0f); }
#pragma unroll
    for (int ks = 0; ks < 8; ++ks) {
      s16x8 b0 = *(const s16x8*)(wbase0 + ks * 512);
      s16x8 b1 = *(const s16x8*)(wbase1 + ks * 512);
#pragma unroll
      for (int m = 0; m < 4; ++m) {
        s16x8 a = *(const s16x8*)&As[(16 * m + colb) * 264 + ks * 32 + g * 8];
        acc[job][m][0] = __builtin_amdgcn_mfma_f32_16x16x32_bf16(a, b0, acc[job][m][0], 0, 0, 0);
        acc[job][m][1] = __builtin_amdgcn_mfma_f32_16x16x32_bf16(a, b1, acc[job][m][1], 0, 0, 0);
      }
    }
  }
  __syncthreads();   // everyone done with As data

  // ---- epilogues: LDS bounce -> coalesced stores ----
#pragma unroll 1
  for (int job = 0; job < 2; ++job) {
    const float* bias = job ? bias1 : bias0;
    unsigned short* o16 = job ? o16_1 : o16_0;
    float* of = job ? of1 : of0;

    if (of) {                               // f32 output (skip connection)
      float* buf = (float*)smem;            // 64 x 260 floats fits 67584B? 64*260*4=66560 OK
#pragma unroll
      for (int j = 0; j < 2; ++j) {
        int col = (2 * w + j) * 16 + colb;
        float bv = bias[col];
#pragma unroll
        for (int m = 0; m < 4; ++m)
#pragma unroll
          for (int r = 0; r < 4; ++r)
            buf[(16 * m + g * 4 + r) * 260 + col] = acc[job][m][j][r] + bv;
      }
      __syncthreads();
#pragma unroll
      for (int i = 0; i < 8; ++i) {
        int flat = tid + i * 512;
        int row = flat >> 6, ch = flat & 63;
        if (fullblk || m0 + row < M)
          *(float4*)(of + (size_t)(m0 + row) * 256 + ch * 4) = *(const float4*)&buf[row * 260 + ch * 4];
      }
    } else {                                // bf16 output
      short* buf = (short*)smem;            // 64 x 264 shorts
#pragma unroll
      for (int j = 0; j < 2; ++j) {
        int col = (2 * w + j) * 16 + colb;
        float bv = bias[col];
#pragma unroll
        for (int m = 0; m < 4; ++m)
#pragma unroll
          for (int r = 0; r < 4; ++r)
            buf[(16 * m + g * 4 + r) * 264 + col] = f2b(acc[job][m][j][r] + bv);
      }
      __syncthreads();
#pragma unroll
      for (int i = 0; i < 4; ++i) {
        int flat = tid + i * 512;
        int row = flat >> 5, ch = flat & 31;
        if (fullblk || m0 + row < M)
          *(s16x8*)(o16 + (size_t)(m0 + row) * 256 + ch * 8) = *(const s16x8*)&buf[row * 264 + ch * 8];
      }
    }
    __syncthreads();   // before next job overwrites buf
  }
}

// ---------------- CSR build ----------------
__global__ __launch_bounds__(256) void csr_count(const int* __restrict__ ei, int* __restrict__ counts) {
  int t = blockIdx.x * 256 + threadIdx.x;
  if (t < E_EDGES) atomicAdd(&counts[ei[E_EDGES + t]], 1);
}

__global__ __launch_bounds__(1024) void csr_scan(const int* __restrict__ counts,
                                                 int* __restrict__ start,
                                                 int* __restrict__ cursor, int n) {
  __shared__ int wsum[16];
  __shared__ int chunk_tot;
  __shared__ int carry_s;
  const int tid = threadIdx.x, lane = tid & 63, wid = tid >> 6;
  if (tid == 0) carry_s = 0;
  __syncthreads();
  for (int base = 0; base < n; base += 1024) {
    int gi = base + tid;
    int x = (gi < n) ? counts[gi] : 0;
    int v = x;
#pragma unroll
    for (int d = 1; d < 64; d <<= 1) {
      int t = __shfl_up(v, d);
      if (lane >= d) v += t;
    }
    if (lane == 63) wsum[wid] = v;
    __syncthreads();
    if (tid == 0) {
      int run = 0;
#pragma unroll
      for (int i = 0; i < 16; ++i) { int t = wsum[i]; wsum[i] = run; run += t; }
      chunk_tot = run;
    }
    __syncthreads();
    if (gi < n) {
      int excl = carry_s + wsum[wid] + v - x;
      start[gi] = excl;
      cursor[gi] = excl;
    }
    __syncthreads();
    if (tid == 0) carry_s += chunk_tot;
  }
  if (tid == 0) start[n] = carry_s;
}

__global__ __launch_bounds__(256) void csr_fill(const int* __restrict__ ei,
                                                int* __restrict__ cursor,
                                                int* __restrict__ eidx, int* __restrict__ esrc) {
  int t = blockIdx.x * 256 + threadIdx.x;
  if (t < E_EDGES) {
    int d = ei[E_EDGES + t];
    int p = atomicAdd(&cursor[d], 1);
    eidx[p] = t;
    esrc[p] = ei[t];
  }
}

// ---------------- edge GEMM v5 + fused alpha ----------------
// e16 = [cos(rel*Wt+bt) | msg] @ We; then, with e still in LDS,
// alpha = q[dst]·(k[src]+e)/sqrt(C) with 8 lanes/edge -> exb (exp stored).
__global__ __launch_bounds__(512) void edge_gemm5(
    const int* __restrict__ ei, const float* __restrict__ tvec,
    const float* __restrict__ lu, const float* __restrict__ msg,
    const float* __restrict__ Wtim, const float* __restrict__ btim,
    const short* __restrict__ WeT, unsigned short* __restrict__ e16g,
    const unsigned short* __restrict__ Q16, const unsigned short* __restrict__ K16,
    float* __restrict__ exb)
{
  __shared__ short attr[64 * 264];
  __shared__ float rel[64];
  __shared__ int srci[64], dsti[64];

  const int tid = threadIdx.x;
  const int l = tid & 63;
  const int w = tid >> 6;
  const int e0 = blockIdx.x * 64;
  const int colb = l & 15;
  const int g = l >> 4;

  const float wt = Wtim[tid & 127], bt = btim[tid & 127];

  if (tid < 64) {
    int s = ei[e0 + tid];
    int d = ei[E_EDGES + e0 + tid];
    srci[tid] = s; dsti[tid] = d;
    rel[tid] = tvec[e0 + tid] - lu[s];
  }
#pragma unroll
  for (int i = 0; i < 4; ++i) {
    int flat = tid + i * 512;
    int row = flat >> 5, c4 = flat & 31;
    float4 mv = *(const float4*)(msg + (size_t)(e0 + row) * 128 + c4 * 4);
    s16x4 sv; sv[0] = f2b(mv.x); sv[1] = f2b(mv.y); sv[2] = f2b(mv.z); sv[3] = f2b(mv.w);
    *(s16x4*)&attr[row * 264 + 128 + c4 * 4] = sv;
  }
  __syncthreads();   // rel + msg staged

  { // time-encoder cols
    int col = tid & 127;
    int r0 = (tid >> 7) * 16;
#pragma unroll
    for (int i = 0; i < 16; ++i)
      attr[(r0 + i) * 264 + col] = f2b(__cosf(rel[r0 + i] * wt + bt));
  }
  __syncthreads();

  const short* wbase0 = WeT + (((2 * w + 0) * 8) * 16 + colb) * 32 + g * 8;
  const short* wbase1 = WeT + (((2 * w + 1) * 8) * 16 + colb) * 32 + g * 8;
  f32x4 acc[4][2];
#pragma unroll
  for (int m = 0; m < 4; ++m) { acc[m][0] = (f32x4)(0.0f); acc[m][1] = (f32x4)(0.0f); }
#pragma unroll
  for (int ks = 0; ks < 8; ++ks) {
    s16x8 b0 = *(const s16x8*)(wbase0 + ks * 512);
    s16x8 b1 = *(const s16x8*)(wbase1 + ks * 512);
#pragma unroll
    for (int m = 0; m < 4; ++m) {
      s16x8 a = *(const s16x8*)&attr[(16 * m + colb) * 264 + ks * 32 + g * 8];
      acc[m][0] = __builtin_amdgcn_mfma_f32_16x16x32_bf16(a, b0, acc[m][0], 0, 0, 0);
      acc[m][1] = __builtin_amdgcn_mfma_f32_16x16x32_bf16(a, b1, acc[m][1], 0, 0, 0);
    }
  }
  __syncthreads();   // all waves done reading attr
#pragma unroll
  for (int j = 0; j < 2; ++j)
#pragma unroll
    for (int m = 0; m < 4; ++m)
#pragma unroll
      for (int r = 0; r < 4; ++r)
        attr[(16 * m + g * 4 + r) * 264 + (2 * w + j) * 16 + colb] = f2b(acc[m][j][r]);
  __syncthreads();

  // stream e (bf16) to global, coalesced 16B stores
#pragma unroll
  for (int i = 0; i < 4; ++i) {
    int flat = tid + i * 512;
    int row = flat >> 5, cg = flat & 31;
    *(s16x8*)(e16g + (size_t)(e0 + row) * 256 + cg * 8) = *(const s16x8*)&attr[row * 264 + cg * 8];
  }

  { // alpha: 8 lanes per edge; 2-shfl reduce within 4-lane head group
    const int er = tid >> 3, ll = tid & 7;
    const int head = ll >> 2, qq = ll & 3;
    const int coff = head * 128 + qq * 32;
    const int s = srci[er], d = dsti[er];
    const unsigned short* qp = Q16 + (size_t)d * 256 + coff;
    const unsigned short* kp = K16 + (size_t)s * 256 + coff;
    const short* ep = &attr[er * 264 + coff];
    float dot = 0.f;
#pragma unroll
    for (int i = 0; i < 4; ++i) {
      s16x8 qv = *(const s16x8*)(qp + i * 8);
      s16x8 kv = *(const s16x8*)(kp + i * 8);
      s16x8 ev = *(const s16x8*)(ep + i * 8);
#pragma unroll
      for (int j = 0; j < 8; ++j)
        dot += b2f((unsigned short)qv[j]) * (b2f((unsigned short)kv[j]) + b2f((unsigned short)ev[j]));
    }
    dot += __shfl_xor(dot, 1);
    dot += __shfl_xor(dot, 2);
    if (qq == 0)
      exb[(size_t)(e0 + er) * 2 + head] = __expf(dot * INV_SQRT_C);
  }
}

// ---------------- aggregate v2: pure-FMA loop, one wave per dst ----------------
__global__ __launch_bounds__(256) void aggregate_fused2(
    const int* __restrict__ start, const int* __restrict__ eidx, const int* __restrict__ esrc,
    const float* __restrict__ exb, const unsigned short* __restrict__ V16,
    const unsigned short* __restrict__ e16, float* __restrict__ out)
{
  const int d = blockIdx.x * 4 + (threadIdx.x >> 6);
  if (d >= N_NODES) return;
  const int lane = threadIdx.x & 63;
  const int s0 = start[d], s1 = start[d + 1];
  if (s1 <= s0) return;                 // out already holds skip
  const int h = lane >> 5;
  const int c0 = lane * 4;

  float den = 0.f;
  float acc0 = 0.f, acc1 = 0.f, acc2 = 0.f, acc3 = 0.f;
  for (int p = s0; p < s1; ++p) {
    int e = eidx[p], s = esrc[p];
    float ex = exb[(size_t)e * 2 + h];
    s16x4 ev = *(const s16x4*)(e16 + (size_t)e * 256 + c0);
    s16x4 vv = *(const s16x4*)(V16 + (size_t)s * 256 + c0);
    den += ex;
    acc0 += ex * (b2f((unsigned short)vv[0]) + b2f((unsigned short)ev[0]));
    acc1 += ex * (b2f((unsigned short)vv[1]) + b2f((unsigned short)ev[1]));
    acc2 += ex * (b2f((unsigned short)vv[2]) + b2f((unsigned short)ev[2]));
    acc3 += ex * (b2f((unsigned short)vv[3]) + b2f((unsigned short)ev[3]));
  }
  float inv = 1.f / (den + 1e-16f);
  float4* op = (float4*)(out + (size_t)d * 256 + c0);
  float4 o = *op;
  o.x += acc0 * inv; o.y += acc1 * inv; o.z += acc2 * inv; o.w += acc3 * inv;
  *op = o;
}

extern "C" void kernel_launch(void* const* d_in, const int* in_sizes, int n_in,
                              void* d_out, int out_size, void* d_ws, size_t ws_size,
                              hipStream_t stream) {
  const float* x_user  = (const float*)d_in[0];
  const float* x_item  = (const float*)d_in[1];
  const float* lu_user = (const float*)d_in[2];
  const float* lu_item = (const float*)d_in[3];
  const int*   ei_a    = (const int*)d_in[4];
  const int*   ei_b    = (const int*)d_in[5];
  const float* t_a     = (const float*)d_in[6];
  const float* t_b     = (const float*)d_in[7];
  const float* msg_a   = (const float*)d_in[8];
  const float* msg_b   = (const float*)d_in[9];
  const float* W_t     = (const float*)d_in[10];
  const float* b_t     = (const float*)d_in[11];
  const float* Wq_a = (const float*)d_in[12]; const float* bq_a = (const float*)d_in[13];
  const float* Wk_a = (const float*)d_in[14]; const float* bk_a = (const float*)d_in[15];
  const float* Wv_a = (const float*)d_in[16]; const float* bv_a = (const float*)d_in[17];
  const float* We_a = (const float*)d_in[18];
  const float* Ws_a = (const float*)d_in[19]; const float* bs_a = (const float*)d_in[20];
  const float* Wq_b = (const float*)d_in[21]; const float* bq_b = (const float*)d_in[22];
  const float* Wk_b = (const float*)d_in[23]; const float* bk_b = (const float*)d_in[24];
  const float* Wv_b = (const float*)d_in[25]; const float* bv_b = (const float*)d_in[26];
  const float* We_b = (const float*)d_in[27];
  const float* Ws_b = (const float*)d_in[28]; const float* bs_b = (const float*)d_in[29];

  float* out_user = (float*)d_out;
  float* out_item = (float*)d_out + (size_t)N_NODES * 256;

  WPtrs wp;
  wp.w[0] = Wq_a; wp.w[1] = Wk_a; wp.w[2] = Wv_a; wp.w[3] = Ws_a; wp.w[4] = We_a;
  wp.w[5] = Wq_b; wp.w[6] = Wk_b; wp.w[7] = Wv_b; wp.w[8] = Ws_b; wp.w[9] = We_b;

  dim3 blk(256);
  dim3 blk512(512);
  dim3 gW(40);
  dim3 gN((N_NODES + 63) / 64);
  dim3 gE(E_EDGES / 64);
  dim3 gEt((E_EDGES + 255) / 256);
  dim3 gAgg((N_NODES + 3) / 4);

  // ws layout: ~184.4 MB (== round-1 proven footprint)
  char* ws = (char*)d_ws;
  size_t off = 0;
  short* WtT = (short*)(ws + off); off += (size_t)10 * 65536 * 2;
  unsigned short* Q16 = (unsigned short*)(ws + off); off += (size_t)N_NODES * 256 * 2;
  unsigned short* K16 = (unsigned short*)(ws + off); off += (size_t)N_NODES * 256 * 2;
  unsigned short* V16 = (unsigned short*)(ws + off); off += (size_t)N_NODES * 256 * 2;
  unsigned short* e16 = (unsigned short*)(ws + off); off += (size_t)E_EDGES * 256 * 2;
  float* exb = (float*)(ws + off); off += (size_t)E_EDGES * 2 * 4;
  int* counts = (int*)(ws + off); off += (size_t)N_NODES * 4;
  int* startb = (int*)(ws + off); off += (size_t)(N_NODES + 4) * 4;
  int* cursor = (int*)(ws + off); off += (size_t)N_NODES * 4;
  int* eidx   = (int*)(ws + off); off += (size_t)E_EDGES * 4;
  int* esrc   = (int*)(ws + off); off += (size_t)E_EDGES * 4;
  if (ws_size < off) return;   // fail loudly (output stays poisoned)

  prep_transpose<<<gW, blk, 0, stream>>>(wp, WtT);

  // ---- type a: user --to--> item (dst=item) ----
  node_gemm5<<<gN, blk512, 0, stream>>>(x_user, N_NODES,
      WtT + 1 * 65536, bk_a, K16, nullptr, WtT + 2 * 65536, bv_a, V16, nullptr);
  node_gemm5<<<gN, blk512, 0, stream>>>(x_item, N_NODES,
      WtT + 0 * 65536, bq_a, Q16, nullptr, WtT + 3 * 65536, bs_a, nullptr, out_item);
  hipMemsetAsync(counts, 0, (size_t)N_NODES * 4, stream);
  csr_count<<<gEt, blk, 0, stream>>>(ei_a, counts);
  csr_scan<<<1, 1024, 0, stream>>>(counts, startb, cursor, N_NODES);
  csr_fill<<<gEt, blk, 0, stream>>>(ei_a, cursor, eidx, esrc);
  edge_gemm5<<<gE, blk512, 0, stream>>>(ei_a, t_a, lu_user, msg_a, W_t, b_t,
      WtT + 4 * 65536, e16, Q16, K16, exb);
  aggregate_fused2<<<gAgg, blk, 0, stream>>>(startb, eidx, esrc, exb, V16, e16, out_item);

  // ---- type b: item --rev_to--> user (dst=user) ----
  node_gemm5<<<gN, blk512, 0, stream>>>(x_item, N_NODES,
      WtT + 6 * 65536, bk_b, K16, nullptr, WtT + 7 * 65536, bv_b, V16, nullptr);
  node_gemm5<<<gN, blk512, 0, stream>>>(x_user, N_NODES,
      WtT + 5 * 65536, bq_b, Q16, nullptr, WtT + 8 * 65536, bs_b, nullptr, out_user);
  hipMemsetAsync(counts, 0, (size_t)N_NODES * 4, stream);
  csr_count<<<gEt, blk, 0, stream>>>(ei_b, counts);
  csr_scan<<<1, 1024, 0, stream>>>(counts, startb, cursor, N_NODES);
  csr_fill<<<gEt, blk, 0, stream>>>(ei_b, cursor, eidx, esrc);
  edge_gemm5<<<gE, blk512, 0, stream>>>(ei_b, t_b, lu_item, msg_b, W_t, b_t,
      WtT + 9 * 65536, e16, Q16, K16, exb);
  aggregate_fused2<<<gAgg, blk, 0, stream>>>(startb, eidx, esrc, exb, V16, e16, out_user);
}

// Round 8
// 672.081 us; speedup vs baseline: 1.1269x; 1.1269x over previous
//
#include <hip/hip_runtime.h>
#include <hip/hip_bf16.h>

#define N_NODES 50000
#define E_EDGES 200000
static constexpr float INV_SQRT_C = 0.08838834764831845f; // 1/sqrt(128)

typedef __attribute__((ext_vector_type(4))) float f32x4;
typedef __attribute__((ext_vector_type(8))) short s16x8;
typedef __attribute__((ext_vector_type(4))) short s16x4;

__device__ __forceinline__ float b2f(unsigned short u) {
  union { unsigned u; float f; } x; x.u = ((unsigned)u) << 16; return x.f;
}
__device__ __forceinline__ short f2b(float f) {
  union { float f; unsigned u; } x; x.f = f;
  unsigned r = x.u + 0x7FFFu + ((x.u >> 16) & 1u);  // RNE
  return (short)(r >> 16);
}

struct WPtrs { const float* w[10]; };

// Repack 10 [256x256] f32 weights into bf16 MFMA-fragment order:
//   out[((ct*8 + ks)*16 + colb)*32 + g*8 + j] = W[ks*32 + g*8 + j][ct*16 + colb]
__global__ __launch_bounds__(256) void prep_transpose(WPtrs p, short* __restrict__ out) {
  __shared__ short T[256 * 66];
  const int wi = blockIdx.x >> 2, cq = blockIdx.x & 3;
  const float* w = p.w[wi];
  short* o = out + wi * 65536;
  const int tid = threadIdx.x;
#pragma unroll
  for (int i = 0; i < 64; ++i) {
    int flat = tid + i * 256;
    int k = flat >> 6, cc = flat & 63;
    T[k * 66 + cc] = f2b(w[k * 256 + cq * 64 + cc]);
  }
  __syncthreads();
#pragma unroll
  for (int i = 0; i < 8; ++i) {
    int flat2 = tid + i * 256;
    int g = flat2 & 3, colb = (flat2 >> 2) & 15, ks = (flat2 >> 6) & 7, ctl = flat2 >> 9;
    int ct = cq * 4 + ctl;
    s16x8 v;
#pragma unroll
    for (int j = 0; j < 8; ++j)
      v[j] = T[(ks * 32 + g * 8 + j) * 66 + ctl * 16 + colb];
    *(s16x8*)(o + (((ct * 8 + ks) * 16 + colb) * 32 + g * 8)) = v;
  }
}

// ---------------- node GEMM v6 ----------------
// One job per block (blockIdx.y). 512 thr / 8 waves, 64 rows/block.
// LDS 33.8KB (As reused as epilogue bounce; f32 job bounces in 2 halves)
// -> 4 blocks/CU. Coalesced epilogue stores via LDS bounce.
__global__ __launch_bounds__(512) void node_gemm6(
    const float* __restrict__ X, int M,
    const short* __restrict__ Wt0, const float* __restrict__ bias0,
    unsigned short* __restrict__ o16_0, float* __restrict__ of0,
    const short* __restrict__ Wt1, const float* __restrict__ bias1,
    unsigned short* __restrict__ o16_1, float* __restrict__ of1)
{
  __shared__ __align__(16) char smem[33792];   // As 64x264 bf16 == bounce buffer
  short* As = (short*)smem;
  const int tid = threadIdx.x;
  const int l = tid & 63;
  const int w = tid >> 6;
  const int m0 = blockIdx.x * 64;
  const bool fullblk = (m0 + 64 <= M);
  const int job = blockIdx.y;
  const short* Wt = job ? Wt1 : Wt0;
  const float* bias = job ? bias1 : bias0;
  unsigned short* o16 = job ? o16_1 : o16_0;
  float* of = job ? of1 : of0;

  if (fullblk) {
#pragma unroll
    for (int i = 0; i < 8; ++i) {
      int flat = tid + i * 512;
      int r = flat >> 6, c4 = flat & 63;
      float4 xv = *(const float4*)(X + (size_t)(m0 + r) * 256 + c4 * 4);
      s16x4 sv; sv[0] = f2b(xv.x); sv[1] = f2b(xv.y); sv[2] = f2b(xv.z); sv[3] = f2b(xv.w);
      *(s16x4*)&As[r * 264 + c4 * 4] = sv;
    }
  } else {
#pragma unroll
    for (int i = 0; i < 8; ++i) {
      int flat = tid + i * 512;
      int r = flat >> 6, c4 = flat & 63;
      float4 xv = make_float4(0.f, 0.f, 0.f, 0.f);
      if (m0 + r < M) xv = *(const float4*)(X + (size_t)(m0 + r) * 256 + c4 * 4);
      s16x4 sv; sv[0] = f2b(xv.x); sv[1] = f2b(xv.y); sv[2] = f2b(xv.z); sv[3] = f2b(xv.w);
      *(s16x4*)&As[r * 264 + c4 * 4] = sv;
    }
  }
  __syncthreads();

  const int colb = l & 15;
  const int g = l >> 4;
  const short* wbase0 = Wt + (((2 * w + 0) * 8) * 16 + colb) * 32 + g * 8;
  const short* wbase1 = Wt + (((2 * w + 1) * 8) * 16 + colb) * 32 + g * 8;

  f32x4 acc[4][2];
#pragma unroll
  for (int m = 0; m < 4; ++m) { acc[m][0] = (f32x4)(0.0f); acc[m][1] = (f32x4)(0.0f); }
#pragma unroll
  for (int ks = 0; ks < 8; ++ks) {
    s16x8 b0 = *(const s16x8*)(wbase0 + ks * 512);
    s16x8 b1 = *(const s16x8*)(wbase1 + ks * 512);
#pragma unroll
    for (int m = 0; m < 4; ++m) {
      s16x8 a = *(const s16x8*)&As[(16 * m + colb) * 264 + ks * 32 + g * 8];
      acc[m][0] = __builtin_amdgcn_mfma_f32_16x16x32_bf16(a, b0, acc[m][0], 0, 0, 0);
      acc[m][1] = __builtin_amdgcn_mfma_f32_16x16x32_bf16(a, b1, acc[m][1], 0, 0, 0);
    }
  }
  __syncthreads();   // done with As data

  if (of) {          // f32 output: bounce 32 rows at a time (buf 32x260 f32 = 33280B)
    float* buf = (float*)smem;
#pragma unroll 1
    for (int half = 0; half < 2; ++half) {
#pragma unroll
      for (int j = 0; j < 2; ++j) {
        int col = (2 * w + j) * 16 + colb;
        float bv = bias[col];
#pragma unroll
        for (int mm = 0; mm < 2; ++mm) {
          int m = half * 2 + mm;
#pragma unroll
          for (int r = 0; r < 4; ++r)
            buf[(16 * mm + g * 4 + r) * 260 + col] = acc[m][j][r] + bv;
        }
      }
      __syncthreads();
#pragma unroll
      for (int i = 0; i < 4; ++i) {
        int flat = tid + i * 512;
        int row = flat >> 6, ch = flat & 63;
        int grow = m0 + half * 32 + row;
        if (fullblk || grow < M)
          *(float4*)(of + (size_t)grow * 256 + ch * 4) = *(const float4*)&buf[row * 260 + ch * 4];
      }
      __syncthreads();
    }
  } else {           // bf16 output: full 64-row bounce (fits exactly)
    short* buf = (short*)smem;
#pragma unroll
    for (int j = 0; j < 2; ++j) {
      int col = (2 * w + j) * 16 + colb;
      float bv = bias[col];
#pragma unroll
      for (int m = 0; m < 4; ++m)
#pragma unroll
        for (int r = 0; r < 4; ++r)
          buf[(16 * m + g * 4 + r) * 264 + col] = f2b(acc[m][j][r] + bv);
    }
    __syncthreads();
#pragma unroll
    for (int i = 0; i < 4; ++i) {
      int flat = tid + i * 512;
      int row = flat >> 5, ch = flat & 31;
      if (fullblk || m0 + row < M)
        *(s16x8*)(o16 + (size_t)(m0 + row) * 256 + ch * 8) = *(const s16x8*)&buf[row * 264 + ch * 8];
    }
  }
}

// ---------------- CSR build ----------------
__global__ __launch_bounds__(256) void csr_count(const int* __restrict__ ei, int* __restrict__ counts) {
  int t = blockIdx.x * 256 + threadIdx.x;
  if (t < E_EDGES) atomicAdd(&counts[ei[E_EDGES + t]], 1);
}

__global__ __launch_bounds__(1024) void csr_scan(const int* __restrict__ counts,
                                                 int* __restrict__ start,
                                                 int* __restrict__ cursor, int n) {
  __shared__ int wsum[16];
  __shared__ int chunk_tot;
  __shared__ int carry_s;
  const int tid = threadIdx.x, lane = tid & 63, wid = tid >> 6;
  if (tid == 0) carry_s = 0;
  __syncthreads();
  for (int base = 0; base < n; base += 1024) {
    int gi = base + tid;
    int x = (gi < n) ? counts[gi] : 0;
    int v = x;
#pragma unroll
    for (int d = 1; d < 64; d <<= 1) {
      int t = __shfl_up(v, d);
      if (lane >= d) v += t;
    }
    if (lane == 63) wsum[wid] = v;
    __syncthreads();
    if (tid == 0) {
      int run = 0;
#pragma unroll
      for (int i = 0; i < 16; ++i) { int t = wsum[i]; wsum[i] = run; run += t; }
      chunk_tot = run;
    }
    __syncthreads();
    if (gi < n) {
      int excl = carry_s + wsum[wid] + v - x;
      start[gi] = excl;
      cursor[gi] = excl;
    }
    __syncthreads();
    if (tid == 0) carry_s += chunk_tot;
  }
  if (tid == 0) start[n] = carry_s;
}

// fill: pos[t] = CSR slot of edge t; esrc[slot] = src(t)
__global__ __launch_bounds__(256) void csr_fill(const int* __restrict__ ei,
                                                int* __restrict__ cursor,
                                                int* __restrict__ pos, int* __restrict__ esrc) {
  int t = blockIdx.x * 256 + threadIdx.x;
  if (t < E_EDGES) {
    int d = ei[E_EDGES + t];
    int p = atomicAdd(&cursor[d], 1);
    pos[t] = p;
    esrc[p] = ei[t];
  }
}

// ---------------- edge GEMM v6: e = [cos(rel*Wt+bt) | msg] @ We ----------------
// Output rows scattered to CSR slots (pos[]) so aggregate reads sequentially.
__global__ __launch_bounds__(512) void edge_gemm6(
    const int* __restrict__ ei, const float* __restrict__ tvec,
    const float* __restrict__ lu, const float* __restrict__ msg,
    const float* __restrict__ Wtim, const float* __restrict__ btim,
    const short* __restrict__ WeT, const int* __restrict__ pos,
    unsigned short* __restrict__ e16g)
{
  __shared__ short attr[64 * 264];
  __shared__ float rel[64];
  __shared__ int poss[64];

  const int tid = threadIdx.x;
  const int l = tid & 63;
  const int w = tid >> 6;
  const int e0 = blockIdx.x * 64;
  const int colb = l & 15;
  const int g = l >> 4;

  const float wt = Wtim[tid & 127], bt = btim[tid & 127];

  if (tid < 64) {
    rel[tid] = tvec[e0 + tid] - lu[ei[e0 + tid]];
    poss[tid] = pos[e0 + tid];
  }
#pragma unroll
  for (int i = 0; i < 4; ++i) {
    int flat = tid + i * 512;
    int row = flat >> 5, c4 = flat & 31;
    float4 mv = *(const float4*)(msg + (size_t)(e0 + row) * 128 + c4 * 4);
    s16x4 sv; sv[0] = f2b(mv.x); sv[1] = f2b(mv.y); sv[2] = f2b(mv.z); sv[3] = f2b(mv.w);
    *(s16x4*)&attr[row * 264 + 128 + c4 * 4] = sv;
  }
  __syncthreads();   // rel + msg staged

  { // time-encoder cols
    int col = tid & 127;
    int r0 = (tid >> 7) * 16;
#pragma unroll
    for (int i = 0; i < 16; ++i)
      attr[(r0 + i) * 264 + col] = f2b(__cosf(rel[r0 + i] * wt + bt));
  }
  __syncthreads();

  const short* wbase0 = WeT + (((2 * w + 0) * 8) * 16 + colb) * 32 + g * 8;
  const short* wbase1 = WeT + (((2 * w + 1) * 8) * 16 + colb) * 32 + g * 8;
  f32x4 acc[4][2];
#pragma unroll
  for (int m = 0; m < 4; ++m) { acc[m][0] = (f32x4)(0.0f); acc[m][1] = (f32x4)(0.0f); }
#pragma unroll
  for (int ks = 0; ks < 8; ++ks) {
    s16x8 b0 = *(const s16x8*)(wbase0 + ks * 512);
    s16x8 b1 = *(const s16x8*)(wbase1 + ks * 512);
#pragma unroll
    for (int m = 0; m < 4; ++m) {
      s16x8 a = *(const s16x8*)&attr[(16 * m + colb) * 264 + ks * 32 + g * 8];
      acc[m][0] = __builtin_amdgcn_mfma_f32_16x16x32_bf16(a, b0, acc[m][0], 0, 0, 0);
      acc[m][1] = __builtin_amdgcn_mfma_f32_16x16x32_bf16(a, b1, acc[m][1], 0, 0, 0);
    }
  }
  __syncthreads();   // all waves done reading attr
#pragma unroll
  for (int j = 0; j < 2; ++j)
#pragma unroll
    for (int m = 0; m < 4; ++m)
#pragma unroll
      for (int r = 0; r < 4; ++r)
        attr[(16 * m + g * 4 + r) * 264 + (2 * w + j) * 16 + colb] = f2b(acc[m][j][r]);
  __syncthreads();

  // scatter e rows to CSR slots; each half-wave writes one full 512B row
#pragma unroll
  for (int i = 0; i < 4; ++i) {
    int flat = tid + i * 512;
    int row = flat >> 5, cg = flat & 31;
    size_t slot = (size_t)poss[row];
    *(s16x8*)(e16g + slot * 256 + cg * 8) = *(const s16x8*)&attr[row * 264 + cg * 8];
  }
}

// ---------------- aggregate v3: fused alpha, sequential e16, 4-way ILP ----------------
__global__ __launch_bounds__(256) void aggregate_fused3(
    const int* __restrict__ start, const int* __restrict__ esrc,
    const unsigned short* __restrict__ Q16, const unsigned short* __restrict__ K16,
    const unsigned short* __restrict__ V16, const unsigned short* __restrict__ e16,
    float* __restrict__ out)
{
  const int d = blockIdx.x * 4 + (threadIdx.x >> 6);
  if (d >= N_NODES) return;
  const int lane = threadIdx.x & 63;
  const int s0 = start[d], s1 = start[d + 1];
  if (s1 <= s0) return;                 // out already holds skip
  const int c0 = lane * 4;              // lanes 0-31: head 0; 32-63: head 1

  s16x4 qv = *(const s16x4*)(Q16 + (size_t)d * 256 + c0);
  const float q0 = b2f((unsigned short)qv[0]), q1 = b2f((unsigned short)qv[1]);
  const float q2 = b2f((unsigned short)qv[2]), q3 = b2f((unsigned short)qv[3]);

  float den = 0.f;
  float a0 = 0.f, a1 = 0.f, a2 = 0.f, a3 = 0.f;
  int p = s0;

#define EDGE_LOAD(J, PP)                                                    \
    int s##J = esrc[PP];                                                    \
    s16x4 ev##J = *(const s16x4*)(e16 + (size_t)(PP) * 256 + c0);           \
    s16x4 kv##J = *(const s16x4*)(K16 + (size_t)s##J * 256 + c0);           \
    s16x4 vv##J = *(const s16x4*)(V16 + (size_t)s##J * 256 + c0);           \
    float e0##J = b2f((unsigned short)ev##J[0]), e1##J = b2f((unsigned short)ev##J[1]); \
    float e2##J = b2f((unsigned short)ev##J[2]), e3##J = b2f((unsigned short)ev##J[3]); \
    float dt##J = q0 * (b2f((unsigned short)kv##J[0]) + e0##J)              \
                + q1 * (b2f((unsigned short)kv##J[1]) + e1##J)              \
                + q2 * (b2f((unsigned short)kv##J[2]) + e2##J)              \
                + q3 * (b2f((unsigned short)kv##J[3]) + e3##J);

#define EDGE_ACC(J)                                                         \
    den += ex##J;                                                           \
    a0 += ex##J * (b2f((unsigned short)vv##J[0]) + e0##J);                  \
    a1 += ex##J * (b2f((unsigned short)vv##J[1]) + e1##J);                  \
    a2 += ex##J * (b2f((unsigned short)vv##J[2]) + e2##J);                  \
    a3 += ex##J * (b2f((unsigned short)vv##J[3]) + e3##J);

  for (; p + 4 <= s1; p += 4) {        // 4 independent chains: shfl/exp latencies overlap
    EDGE_LOAD(A, p)  EDGE_LOAD(B, p + 1)  EDGE_LOAD(C, p + 2)  EDGE_LOAD(D, p + 3)
    dtA += __shfl_xor(dtA, 1);  dtB += __shfl_xor(dtB, 1);
    dtC += __shfl_xor(dtC, 1);  dtD += __shfl_xor(dtD, 1);
    dtA += __shfl_xor(dtA, 2);  dtB += __shfl_xor(dtB, 2);
    dtC += __shfl_xor(dtC, 2);  dtD += __shfl_xor(dtD, 2);
    dtA += __shfl_xor(dtA, 4);  dtB += __shfl_xor(dtB, 4);
    dtC += __shfl_xor(dtC, 4);  dtD += __shfl_xor(dtD, 4);
    dtA += __shfl_xor(dtA, 8);  dtB += __shfl_xor(dtB, 8);
    dtC += __shfl_xor(dtC, 8);  dtD += __shfl_xor(dtD, 8);
    dtA += __shfl_xor(dtA, 16); dtB += __shfl_xor(dtB, 16);
    dtC += __shfl_xor(dtC, 16); dtD += __shfl_xor(dtD, 16);
    float exA = __expf(dtA * INV_SQRT_C), exB = __expf(dtB * INV_SQRT_C);
    float exC = __expf(dtC * INV_SQRT_C), exD = __expf(dtD * INV_SQRT_C);
    EDGE_ACC(A) EDGE_ACC(B) EDGE_ACC(C) EDGE_ACC(D)
  }
  for (; p < s1; ++p) {                // tail
    EDGE_LOAD(T, p)
    dtT += __shfl_xor(dtT, 1);
    dtT += __shfl_xor(dtT, 2);
    dtT += __shfl_xor(dtT, 4);
    dtT += __shfl_xor(dtT, 8);
    dtT += __shfl_xor(dtT, 16);
    float exT = __expf(dtT * INV_SQRT_C);
    EDGE_ACC(T)
  }
#undef EDGE_LOAD
#undef EDGE_ACC

  float inv = 1.f / (den + 1e-16f);
  float4* op = (float4*)(out + (size_t)d * 256 + c0);
  float4 o = *op;
  o.x += a0 * inv; o.y += a1 * inv; o.z += a2 * inv; o.w += a3 * inv;
  *op = o;
}

extern "C" void kernel_launch(void* const* d_in, const int* in_sizes, int n_in,
                              void* d_out, int out_size, void* d_ws, size_t ws_size,
                              hipStream_t stream) {
  const float* x_user  = (const float*)d_in[0];
  const float* x_item  = (const float*)d_in[1];
  const float* lu_user = (const float*)d_in[2];
  const float* lu_item = (const float*)d_in[3];
  const int*   ei_a    = (const int*)d_in[4];
  const int*   ei_b    = (const int*)d_in[5];
  const float* t_a     = (const float*)d_in[6];
  const float* t_b     = (const float*)d_in[7];
  const float* msg_a   = (const float*)d_in[8];
  const float* msg_b   = (const float*)d_in[9];
  const float* W_t     = (const float*)d_in[10];
  const float* b_t     = (const float*)d_in[11];
  const float* Wq_a = (const float*)d_in[12]; const float* bq_a = (const float*)d_in[13];
  const float* Wk_a = (const float*)d_in[14]; const float* bk_a = (const float*)d_in[15];
  const float* Wv_a = (const float*)d_in[16]; const float* bv_a = (const float*)d_in[17];
  const float* We_a = (const float*)d_in[18];
  const float* Ws_a = (const float*)d_in[19]; const float* bs_a = (const float*)d_in[20];
  const float* Wq_b = (const float*)d_in[21]; const float* bq_b = (const float*)d_in[22];
  const float* Wk_b = (const float*)d_in[23]; const float* bk_b = (const float*)d_in[24];
  const float* Wv_b = (const float*)d_in[25]; const float* bv_b = (const float*)d_in[26];
  const float* We_b = (const float*)d_in[27];
  const float* Ws_b = (const float*)d_in[28]; const float* bs_b = (const float*)d_in[29];

  float* out_user = (float*)d_out;
  float* out_item = (float*)d_out + (size_t)N_NODES * 256;

  WPtrs wp;
  wp.w[0] = Wq_a; wp.w[1] = Wk_a; wp.w[2] = Wv_a; wp.w[3] = Ws_a; wp.w[4] = We_a;
  wp.w[5] = Wq_b; wp.w[6] = Wk_b; wp.w[7] = Wv_b; wp.w[8] = Ws_b; wp.w[9] = We_b;

  dim3 blk(256);
  dim3 blk512(512);
  dim3 gW(40);
  dim3 gN2((N_NODES + 63) / 64, 2);
  dim3 gE(E_EDGES / 64);
  dim3 gEt((E_EDGES + 255) / 256);
  dim3 gAgg((N_NODES + 3) / 4);

  // ws layout: ~183 MB
  char* ws = (char*)d_ws;
  size_t off = 0;
  short* WtT = (short*)(ws + off); off += (size_t)10 * 65536 * 2;
  unsigned short* Q16 = (unsigned short*)(ws + off); off += (size_t)N_NODES * 256 * 2;
  unsigned short* K16 = (unsigned short*)(ws + off); off += (size_t)N_NODES * 256 * 2;
  unsigned short* V16 = (unsigned short*)(ws + off); off += (size_t)N_NODES * 256 * 2;
  unsigned short* e16 = (unsigned short*)(ws + off); off += (size_t)E_EDGES * 256 * 2;
  int* pos    = (int*)(ws + off); off += (size_t)E_EDGES * 4;
  int* counts = (int*)(ws + off); off += (size_t)N_NODES * 4;
  int* startb = (int*)(ws + off); off += (size_t)(N_NODES + 4) * 4;
  int* cursor = (int*)(ws + off); off += (size_t)N_NODES * 4;
  int* esrc   = (int*)(ws + off); off += (size_t)E_EDGES * 4;
  if (ws_size < off) return;   // fail loudly (output stays poisoned)

  prep_transpose<<<gW, blk, 0, stream>>>(wp, WtT);

  // ---- type a: user --to--> item (dst=item) ----
  node_gemm6<<<gN2, blk512, 0, stream>>>(x_user, N_NODES,
      WtT + 1 * 65536, bk_a, K16, nullptr, WtT + 2 * 65536, bv_a, V16, nullptr);
  node_gemm6<<<gN2, blk512, 0, stream>>>(x_item, N_NODES,
      WtT + 0 * 65536, bq_a, Q16, nullptr, WtT + 3 * 65536, bs_a, nullptr, out_item);
  hipMemsetAsync(counts, 0, (size_t)N_NODES * 4, stream);
  csr_count<<<gEt, blk, 0, stream>>>(ei_a, counts);
  csr_scan<<<1, 1024, 0, stream>>>(counts, startb, cursor, N_NODES);
  csr_fill<<<gEt, blk, 0, stream>>>(ei_a, cursor, pos, esrc);
  edge_gemm6<<<gE, blk512, 0, stream>>>(ei_a, t_a, lu_user, msg_a, W_t, b_t,
      WtT + 4 * 65536, pos, e16);
  aggregate_fused3<<<gAgg, blk, 0, stream>>>(startb, esrc, Q16, K16, V16, e16, out_item);

  // ---- type b: item --rev_to--> user (dst=user) ----
  node_gemm6<<<gN2, blk512, 0, stream>>>(x_item, N_NODES,
      WtT + 6 * 65536, bk_b, K16, nullptr, WtT + 7 * 65536, bv_b, V16, nullptr);
  node_gemm6<<<gN2, blk512, 0, stream>>>(x_user, N_NODES,
      WtT + 5 * 65536, bq_b, Q16, nullptr, WtT + 8 * 65536, bs_b, nullptr, out_user);
  hipMemsetAsync(counts, 0, (size_t)N_NODES * 4, stream);
  csr_count<<<gEt, blk, 0, stream>>>(ei_b, counts);
  csr_scan<<<1, 1024, 0, stream>>>(counts, startb, cursor, N_NODES);
  csr_fill<<<gEt, blk, 0, stream>>>(ei_b, cursor, pos, esrc);
  edge_gemm6<<<gE, blk512, 0, stream>>>(ei_b, t_b, lu_item, msg_b, W_t, b_t,
      WtT + 9 * 65536, pos, e16);
  aggregate_fused3<<<gAgg, blk, 0, stream>>>(startb, esrc, Q16, K16, V16, e16, out_user);
}

// Round 9
// 573.206 us; speedup vs baseline: 1.3213x; 1.1725x over previous
//
#include <hip/hip_runtime.h>
#include <hip/hip_bf16.h>

#define N_NODES 50000
#define E_EDGES 200000
static constexpr float INV_SQRT_C = 0.08838834764831845f; // 1/sqrt(128)

typedef __attribute__((ext_vector_type(4))) float f32x4;
typedef __attribute__((ext_vector_type(8))) short s16x8;
typedef __attribute__((ext_vector_type(4))) short s16x4;

__device__ __forceinline__ float b2f(unsigned short u) {
  union { unsigned u; float f; } x; x.u = ((unsigned)u) << 16; return x.f;
}
__device__ __forceinline__ short f2b(float f) {
  union { float f; unsigned u; } x; x.f = f;
  unsigned r = x.u + 0x7FFFu + ((x.u >> 16) & 1u);  // RNE
  return (short)(r >> 16);
}

struct WPtrs { const float* w[10]; };

// Repack 10 [256x256] f32 weights into bf16 MFMA-fragment order:
//   out[((ct*8 + ks)*16 + colb)*32 + g*8 + j] = W[ks*32 + g*8 + j][ct*16 + colb]
__global__ __launch_bounds__(256) void prep_transpose(WPtrs p, short* __restrict__ out) {
  __shared__ short T[256 * 66];
  const int wi = blockIdx.x >> 2, cq = blockIdx.x & 3;
  const float* w = p.w[wi];
  short* o = out + wi * 65536;
  const int tid = threadIdx.x;
#pragma unroll
  for (int i = 0; i < 64; ++i) {
    int flat = tid + i * 256;
    int k = flat >> 6, cc = flat & 63;
    T[k * 66 + cc] = f2b(w[k * 256 + cq * 64 + cc]);
  }
  __syncthreads();
#pragma unroll
  for (int i = 0; i < 8; ++i) {
    int flat2 = tid + i * 256;
    int g = flat2 & 3, colb = (flat2 >> 2) & 15, ks = (flat2 >> 6) & 7, ctl = flat2 >> 9;
    int ct = cq * 4 + ctl;
    s16x8 v;
#pragma unroll
    for (int j = 0; j < 8; ++j)
      v[j] = T[(ks * 32 + g * 8 + j) * 66 + ctl * 16 + colb];
    *(s16x8*)(o + (((ct * 8 + ks) * 16 + colb) * 32 + g * 8)) = v;
  }
}

// ---------------- node GEMM v8: all 4 jobs of one edge type in one dispatch ----
// grid (782, 4): blockIdx.y picks (X, Wt, bias, out). Block body = proven v6.
struct NJobs {
  const float* X[4];
  const short* Wt[4];
  const float* bias[4];
  unsigned short* o16[4];   // null where of used
  float* of[4];             // only job 3 (skip, f32)
};

__global__ __launch_bounds__(512) void node_gemm8(NJobs jobs, int M) {
  __shared__ __align__(16) char smem[33792];   // As 64x264 bf16 == bounce buffer
  short* As = (short*)smem;
  const int tid = threadIdx.x;
  const int l = tid & 63;
  const int w = tid >> 6;
  const int m0 = blockIdx.x * 64;
  const bool fullblk = (m0 + 64 <= M);
  const int job = blockIdx.y;
  const float* X = jobs.X[job];
  const short* Wt = jobs.Wt[job];
  const float* bias = jobs.bias[job];
  unsigned short* o16 = jobs.o16[job];
  float* of = jobs.of[job];

  if (fullblk) {
#pragma unroll
    for (int i = 0; i < 8; ++i) {
      int flat = tid + i * 512;
      int r = flat >> 6, c4 = flat & 63;
      float4 xv = *(const float4*)(X + (size_t)(m0 + r) * 256 + c4 * 4);
      s16x4 sv; sv[0] = f2b(xv.x); sv[1] = f2b(xv.y); sv[2] = f2b(xv.z); sv[3] = f2b(xv.w);
      *(s16x4*)&As[r * 264 + c4 * 4] = sv;
    }
  } else {
#pragma unroll
    for (int i = 0; i < 8; ++i) {
      int flat = tid + i * 512;
      int r = flat >> 6, c4 = flat & 63;
      float4 xv = make_float4(0.f, 0.f, 0.f, 0.f);
      if (m0 + r < M) xv = *(const float4*)(X + (size_t)(m0 + r) * 256 + c4 * 4);
      s16x4 sv; sv[0] = f2b(xv.x); sv[1] = f2b(xv.y); sv[2] = f2b(xv.z); sv[3] = f2b(xv.w);
      *(s16x4*)&As[r * 264 + c4 * 4] = sv;
    }
  }
  __syncthreads();

  const int colb = l & 15;
  const int g = l >> 4;
  const short* wbase0 = Wt + (((2 * w + 0) * 8) * 16 + colb) * 32 + g * 8;
  const short* wbase1 = Wt + (((2 * w + 1) * 8) * 16 + colb) * 32 + g * 8;

  f32x4 acc[4][2];
#pragma unroll
  for (int m = 0; m < 4; ++m) { acc[m][0] = (f32x4)(0.0f); acc[m][1] = (f32x4)(0.0f); }
#pragma unroll
  for (int ks = 0; ks < 8; ++ks) {
    s16x8 b0 = *(const s16x8*)(wbase0 + ks * 512);
    s16x8 b1 = *(const s16x8*)(wbase1 + ks * 512);
#pragma unroll
    for (int m = 0; m < 4; ++m) {
      s16x8 a = *(const s16x8*)&As[(16 * m + colb) * 264 + ks * 32 + g * 8];
      acc[m][0] = __builtin_amdgcn_mfma_f32_16x16x32_bf16(a, b0, acc[m][0], 0, 0, 0);
      acc[m][1] = __builtin_amdgcn_mfma_f32_16x16x32_bf16(a, b1, acc[m][1], 0, 0, 0);
    }
  }
  __syncthreads();   // done with As data

  if (of) {          // f32 output: bounce 32 rows at a time (32x260 f32 = 33280B)
    float* buf = (float*)smem;
#pragma unroll 1
    for (int half = 0; half < 2; ++half) {
#pragma unroll
      for (int j = 0; j < 2; ++j) {
        int col = (2 * w + j) * 16 + colb;
        float bv = bias[col];
#pragma unroll
        for (int mm = 0; mm < 2; ++mm) {
          int m = half * 2 + mm;
#pragma unroll
          for (int r = 0; r < 4; ++r)
            buf[(16 * mm + g * 4 + r) * 260 + col] = acc[m][j][r] + bv;
        }
      }
      __syncthreads();
#pragma unroll
      for (int i = 0; i < 4; ++i) {
        int flat = tid + i * 512;
        int row = flat >> 6, ch = flat & 63;
        int grow = m0 + half * 32 + row;
        if (fullblk || grow < M)
          *(float4*)(of + (size_t)grow * 256 + ch * 4) = *(const float4*)&buf[row * 260 + ch * 4];
      }
      __syncthreads();
    }
  } else {           // bf16 output: full 64-row bounce (fits exactly)
    short* buf = (short*)smem;
#pragma unroll
    for (int j = 0; j < 2; ++j) {
      int col = (2 * w + j) * 16 + colb;
      float bv = bias[col];
#pragma unroll
      for (int m = 0; m < 4; ++m)
#pragma unroll
        for (int r = 0; r < 4; ++r)
          buf[(16 * m + g * 4 + r) * 264 + col] = f2b(acc[m][j][r] + bv);
    }
    __syncthreads();
#pragma unroll
    for (int i = 0; i < 4; ++i) {
      int flat = tid + i * 512;
      int row = flat >> 5, ch = flat & 31;
      if (fullblk || m0 + row < M)
        *(s16x8*)(o16 + (size_t)(m0 + row) * 256 + ch * 8) = *(const s16x8*)&buf[row * 264 + ch * 8];
    }
  }
}

// ---------------- CSR build: both edge types at once ----------------
__global__ __launch_bounds__(256) void csr_count2(const int* __restrict__ eia,
                                                  const int* __restrict__ eib,
                                                  int* __restrict__ counts) {
  int t = blockIdx.x * 256 + threadIdx.x;
  const int* ei = blockIdx.y ? eib : eia;
  int* c = counts + blockIdx.y * N_NODES;
  if (t < E_EDGES) atomicAdd(&c[ei[E_EDGES + t]], 1);
}

// grid 2 (one block per type); cursor written in-place into counts
__global__ __launch_bounds__(1024) void csr_scan2(int* __restrict__ counts,
                                                  int* __restrict__ start) {
  int* cnt = counts + blockIdx.x * N_NODES;
  int* st  = start + blockIdx.x * (N_NODES + 1);
  __shared__ int wsum[16];
  __shared__ int chunk_tot;
  __shared__ int carry_s;
  const int tid = threadIdx.x, lane = tid & 63, wid = tid >> 6;
  if (tid == 0) carry_s = 0;
  __syncthreads();
  for (int base = 0; base < N_NODES; base += 1024) {
    int gi = base + tid;
    int x = (gi < N_NODES) ? cnt[gi] : 0;
    int v = x;
#pragma unroll
    for (int d = 1; d < 64; d <<= 1) {
      int t = __shfl_up(v, d);
      if (lane >= d) v += t;
    }
    if (lane == 63) wsum[wid] = v;
    __syncthreads();
    if (tid == 0) {
      int run = 0;
#pragma unroll
      for (int i = 0; i < 16; ++i) { int t = wsum[i]; wsum[i] = run; run += t; }
      chunk_tot = run;
    }
    __syncthreads();
    if (gi < N_NODES) {
      int excl = carry_s + wsum[wid] + v - x;
      st[gi] = excl;
      cnt[gi] = excl;       // becomes the fill cursor
    }
    __syncthreads();
    if (tid == 0) carry_s += chunk_tot;
  }
  if (tid == 0) st[N_NODES] = carry_s;
}

__global__ __launch_bounds__(256) void csr_fill2(const int* __restrict__ eia,
                                                 const int* __restrict__ eib,
                                                 int* __restrict__ counts,
                                                 int* __restrict__ pos,
                                                 unsigned short* __restrict__ esrc) {
  int t = blockIdx.x * 256 + threadIdx.x;
  const int* ei = blockIdx.y ? eib : eia;
  int* cur = counts + blockIdx.y * N_NODES;
  int* ps  = pos + blockIdx.y * E_EDGES;
  unsigned short* es = esrc + (size_t)blockIdx.y * E_EDGES;
  if (t < E_EDGES) {
    int d = ei[E_EDGES + t];
    int p = atomicAdd(&cur[d], 1);
    ps[t] = p;
    es[p] = (unsigned short)ei[t];
  }
}

// ---------------- edge GEMM v6: e = [cos(rel*Wt+bt) | msg] @ We ----------------
// Output rows scattered to CSR slots (pos[]) so aggregate reads sequentially.
__global__ __launch_bounds__(512) void edge_gemm6(
    const int* __restrict__ ei, const float* __restrict__ tvec,
    const float* __restrict__ lu, const float* __restrict__ msg,
    const float* __restrict__ Wtim, const float* __restrict__ btim,
    const short* __restrict__ WeT, const int* __restrict__ pos,
    unsigned short* __restrict__ e16g)
{
  __shared__ short attr[64 * 264];
  __shared__ float rel[64];
  __shared__ int poss[64];

  const int tid = threadIdx.x;
  const int l = tid & 63;
  const int w = tid >> 6;
  const int e0 = blockIdx.x * 64;
  const int colb = l & 15;
  const int g = l >> 4;

  const float wt = Wtim[tid & 127], bt = btim[tid & 127];

  if (tid < 64) {
    rel[tid] = tvec[e0 + tid] - lu[ei[e0 + tid]];
    poss[tid] = pos[e0 + tid];
  }
#pragma unroll
  for (int i = 0; i < 4; ++i) {
    int flat = tid + i * 512;
    int row = flat >> 5, c4 = flat & 31;
    float4 mv = *(const float4*)(msg + (size_t)(e0 + row) * 128 + c4 * 4);
    s16x4 sv; sv[0] = f2b(mv.x); sv[1] = f2b(mv.y); sv[2] = f2b(mv.z); sv[3] = f2b(mv.w);
    *(s16x4*)&attr[row * 264 + 128 + c4 * 4] = sv;
  }
  __syncthreads();   // rel + msg staged

  { // time-encoder cols
    int col = tid & 127;
    int r0 = (tid >> 7) * 16;
#pragma unroll
    for (int i = 0; i < 16; ++i)
      attr[(r0 + i) * 264 + col] = f2b(__cosf(rel[r0 + i] * wt + bt));
  }
  __syncthreads();

  const short* wbase0 = WeT + (((2 * w + 0) * 8) * 16 + colb) * 32 + g * 8;
  const short* wbase1 = WeT + (((2 * w + 1) * 8) * 16 + colb) * 32 + g * 8;
  f32x4 acc[4][2];
#pragma unroll
  for (int m = 0; m < 4; ++m) { acc[m][0] = (f32x4)(0.0f); acc[m][1] = (f32x4)(0.0f); }
#pragma unroll
  for (int ks = 0; ks < 8; ++ks) {
    s16x8 b0 = *(const s16x8*)(wbase0 + ks * 512);
    s16x8 b1 = *(const s16x8*)(wbase1 + ks * 512);
#pragma unroll
    for (int m = 0; m < 4; ++m) {
      s16x8 a = *(const s16x8*)&attr[(16 * m + colb) * 264 + ks * 32 + g * 8];
      acc[m][0] = __builtin_amdgcn_mfma_f32_16x16x32_bf16(a, b0, acc[m][0], 0, 0, 0);
      acc[m][1] = __builtin_amdgcn_mfma_f32_16x16x32_bf16(a, b1, acc[m][1], 0, 0, 0);
    }
  }
  __syncthreads();   // all waves done reading attr
#pragma unroll
  for (int j = 0; j < 2; ++j)
#pragma unroll
    for (int m = 0; m < 4; ++m)
#pragma unroll
      for (int r = 0; r < 4; ++r)
        attr[(16 * m + g * 4 + r) * 264 + (2 * w + j) * 16 + colb] = f2b(acc[m][j][r]);
  __syncthreads();

  // scatter e rows to CSR slots; each half-wave writes one full 512B row
#pragma unroll
  for (int i = 0; i < 4; ++i) {
    int flat = tid + i * 512;
    int row = flat >> 5, cg = flat & 31;
    size_t slot = (size_t)poss[row];
    *(s16x8*)(e16g + slot * 256 + cg * 8) = *(const s16x8*)&attr[row * 264 + cg * 8];
  }
}

// ---------------- aggregate v4: 128-thr blocks (2 dsts) to cut imbalance ------
__global__ __launch_bounds__(128) void aggregate_fused4(
    const int* __restrict__ start, const unsigned short* __restrict__ esrc,
    const unsigned short* __restrict__ Q16, const unsigned short* __restrict__ K16,
    const unsigned short* __restrict__ V16, const unsigned short* __restrict__ e16,
    float* __restrict__ out)
{
  const int d = blockIdx.x * 2 + (threadIdx.x >> 6);
  if (d >= N_NODES) return;
  const int lane = threadIdx.x & 63;
  const int s0 = start[d], s1 = start[d + 1];
  if (s1 <= s0) return;                 // out already holds skip
  const int c0 = lane * 4;              // lanes 0-31: head 0; 32-63: head 1

  s16x4 qv = *(const s16x4*)(Q16 + (size_t)d * 256 + c0);
  const float q0 = b2f((unsigned short)qv[0]), q1 = b2f((unsigned short)qv[1]);
  const float q2 = b2f((unsigned short)qv[2]), q3 = b2f((unsigned short)qv[3]);

  float den = 0.f;
  float a0 = 0.f, a1 = 0.f, a2 = 0.f, a3 = 0.f;
  int p = s0;

#define EDGE_LOAD(J, PP)                                                    \
    int s##J = (int)esrc[PP];                                               \
    s16x4 ev##J = *(const s16x4*)(e16 + (size_t)(PP) * 256 + c0);           \
    s16x4 kv##J = *(const s16x4*)(K16 + (size_t)s##J * 256 + c0);           \
    s16x4 vv##J = *(const s16x4*)(V16 + (size_t)s##J * 256 + c0);           \
    float e0##J = b2f((unsigned short)ev##J[0]), e1##J = b2f((unsigned short)ev##J[1]); \
    float e2##J = b2f((unsigned short)ev##J[2]), e3##J = b2f((unsigned short)ev##J[3]); \
    float dt##J = q0 * (b2f((unsigned short)kv##J[0]) + e0##J)              \
                + q1 * (b2f((unsigned short)kv##J[1]) + e1##J)              \
                + q2 * (b2f((unsigned short)kv##J[2]) + e2##J)              \
                + q3 * (b2f((unsigned short)kv##J[3]) + e3##J);

#define EDGE_ACC(J)                                                         \
    den += ex##J;                                                           \
    a0 += ex##J * (b2f((unsigned short)vv##J[0]) + e0##J);                  \
    a1 += ex##J * (b2f((unsigned short)vv##J[1]) + e1##J);                  \
    a2 += ex##J * (b2f((unsigned short)vv##J[2]) + e2##J);                  \
    a3 += ex##J * (b2f((unsigned short)vv##J[3]) + e3##J);

  for (; p + 4 <= s1; p += 4) {        // 4 independent chains overlap shfl/exp
    EDGE_LOAD(A, p)  EDGE_LOAD(B, p + 1)  EDGE_LOAD(C, p + 2)  EDGE_LOAD(D, p + 3)
    dtA += __shfl_xor(dtA, 1);  dtB += __shfl_xor(dtB, 1);
    dtC += __shfl_xor(dtC, 1);  dtD += __shfl_xor(dtD, 1);
    dtA += __shfl_xor(dtA, 2);  dtB += __shfl_xor(dtB, 2);
    dtC += __shfl_xor(dtC, 2);  dtD += __shfl_xor(dtD, 2);
    dtA += __shfl_xor(dtA, 4);  dtB += __shfl_xor(dtB, 4);
    dtC += __shfl_xor(dtC, 4);  dtD += __shfl_xor(dtD, 4);
    dtA += __shfl_xor(dtA, 8);  dtB += __shfl_xor(dtB, 8);
    dtC += __shfl_xor(dtC, 8);  dtD += __shfl_xor(dtD, 8);
    dtA += __shfl_xor(dtA, 16); dtB += __shfl_xor(dtB, 16);
    dtC += __shfl_xor(dtC, 16); dtD += __shfl_xor(dtD, 16);
    float exA = __expf(dtA * INV_SQRT_C), exB = __expf(dtB * INV_SQRT_C);
    float exC = __expf(dtC * INV_SQRT_C), exD = __expf(dtD * INV_SQRT_C);
    EDGE_ACC(A) EDGE_ACC(B) EDGE_ACC(C) EDGE_ACC(D)
  }
  for (; p < s1; ++p) {                // tail
    EDGE_LOAD(T, p)
    dtT += __shfl_xor(dtT, 1);
    dtT += __shfl_xor(dtT, 2);
    dtT += __shfl_xor(dtT, 4);
    dtT += __shfl_xor(dtT, 8);
    dtT += __shfl_xor(dtT, 16);
    float exT = __expf(dtT * INV_SQRT_C);
    EDGE_ACC(T)
  }
#undef EDGE_LOAD
#undef EDGE_ACC

  float inv = 1.f / (den + 1e-16f);
  float4* op = (float4*)(out + (size_t)d * 256 + c0);
  float4 o = *op;
  o.x += a0 * inv; o.y += a1 * inv; o.z += a2 * inv; o.w += a3 * inv;
  *op = o;
}

extern "C" void kernel_launch(void* const* d_in, const int* in_sizes, int n_in,
                              void* d_out, int out_size, void* d_ws, size_t ws_size,
                              hipStream_t stream) {
  const float* x_user  = (const float*)d_in[0];
  const float* x_item  = (const float*)d_in[1];
  const float* lu_user = (const float*)d_in[2];
  const float* lu_item = (const float*)d_in[3];
  const int*   ei_a    = (const int*)d_in[4];
  const int*   ei_b    = (const int*)d_in[5];
  const float* t_a     = (const float*)d_in[6];
  const float* t_b     = (const float*)d_in[7];
  const float* msg_a   = (const float*)d_in[8];
  const float* msg_b   = (const float*)d_in[9];
  const float* W_t     = (const float*)d_in[10];
  const float* b_t     = (const float*)d_in[11];
  const float* Wq_a = (const float*)d_in[12]; const float* bq_a = (const float*)d_in[13];
  const float* Wk_a = (const float*)d_in[14]; const float* bk_a = (const float*)d_in[15];
  const float* Wv_a = (const float*)d_in[16]; const float* bv_a = (const float*)d_in[17];
  const float* We_a = (const float*)d_in[18];
  const float* Ws_a = (const float*)d_in[19]; const float* bs_a = (const float*)d_in[20];
  const float* Wq_b = (const float*)d_in[21]; const float* bq_b = (const float*)d_in[22];
  const float* Wk_b = (const float*)d_in[23]; const float* bk_b = (const float*)d_in[24];
  const float* Wv_b = (const float*)d_in[25]; const float* bv_b = (const float*)d_in[26];
  const float* We_b = (const float*)d_in[27];
  const float* Ws_b = (const float*)d_in[28]; const float* bs_b = (const float*)d_in[29];

  float* out_user = (float*)d_out;
  float* out_item = (float*)d_out + (size_t)N_NODES * 256;

  WPtrs wp;
  wp.w[0] = Wq_a; wp.w[1] = Wk_a; wp.w[2] = Wv_a; wp.w[3] = Ws_a; wp.w[4] = We_a;
  wp.w[5] = Wq_b; wp.w[6] = Wk_b; wp.w[7] = Wv_b; wp.w[8] = Ws_b; wp.w[9] = We_b;

  dim3 blk(256);
  dim3 blk512(512);
  dim3 gW(40);
  dim3 gN4((N_NODES + 63) / 64, 4);
  dim3 gE(E_EDGES / 64);
  dim3 gEt2((E_EDGES + 255) / 256, 2);
  dim3 gAgg((N_NODES + 1) / 2);

  // ws layout: ~183.7 MB (under proven 184.3 cap)
  char* ws = (char*)d_ws;
  size_t off = 0;
  short* WtT = (short*)(ws + off); off += (size_t)10 * 65536 * 2;
  unsigned short* Q16 = (unsigned short*)(ws + off); off += (size_t)N_NODES * 256 * 2;
  unsigned short* K16 = (unsigned short*)(ws + off); off += (size_t)N_NODES * 256 * 2;
  unsigned short* V16 = (unsigned short*)(ws + off); off += (size_t)N_NODES * 256 * 2;
  unsigned short* e16 = (unsigned short*)(ws + off); off += (size_t)E_EDGES * 256 * 2;
  int* pos    = (int*)(ws + off); off += (size_t)2 * E_EDGES * 4;
  int* counts = (int*)(ws + off); off += (size_t)2 * N_NODES * 4;     // doubles as cursor
  int* startb = (int*)(ws + off); off += (size_t)2 * (N_NODES + 1) * 4;
  unsigned short* esrc = (unsigned short*)(ws + off); off += (size_t)2 * E_EDGES * 2;
  if (ws_size < off) return;   // fail loudly (output stays poisoned)

  prep_transpose<<<gW, blk, 0, stream>>>(wp, WtT);

  // ---- CSR for both types upfront ----
  hipMemsetAsync(counts, 0, (size_t)2 * N_NODES * 4, stream);
  csr_count2<<<gEt2, blk, 0, stream>>>(ei_a, ei_b, counts);
  csr_scan2<<<2, 1024, 0, stream>>>(counts, startb);
  csr_fill2<<<gEt2, blk, 0, stream>>>(ei_a, ei_b, counts, pos, esrc);

  // ---- type a: user --to--> item (dst=item) ----
  {
    NJobs ja;
    ja.X[0] = x_user; ja.X[1] = x_user; ja.X[2] = x_item; ja.X[3] = x_item;
    ja.Wt[0] = WtT + 1 * 65536; ja.Wt[1] = WtT + 2 * 65536;
    ja.Wt[2] = WtT + 0 * 65536; ja.Wt[3] = WtT + 3 * 65536;
    ja.bias[0] = bk_a; ja.bias[1] = bv_a; ja.bias[2] = bq_a; ja.bias[3] = bs_a;
    ja.o16[0] = K16; ja.o16[1] = V16; ja.o16[2] = Q16; ja.o16[3] = nullptr;
    ja.of[0] = nullptr; ja.of[1] = nullptr; ja.of[2] = nullptr; ja.of[3] = out_item;
    node_gemm8<<<gN4, blk512, 0, stream>>>(ja, N_NODES);
  }
  edge_gemm6<<<gE, blk512, 0, stream>>>(ei_a, t_a, lu_user, msg_a, W_t, b_t,
      WtT + 4 * 65536, pos, e16);
  aggregate_fused4<<<gAgg, 128, 0, stream>>>(startb, esrc, Q16, K16, V16, e16, out_item);

  // ---- type b: item --rev_to--> user (dst=user) ----
  {
    NJobs jb;
    jb.X[0] = x_item; jb.X[1] = x_item; jb.X[2] = x_user; jb.X[3] = x_user;
    jb.Wt[0] = WtT + 6 * 65536; jb.Wt[1] = WtT + 7 * 65536;
    jb.Wt[2] = WtT + 5 * 65536; jb.Wt[3] = WtT + 8 * 65536;
    jb.bias[0] = bk_b; jb.bias[1] = bv_b; jb.bias[2] = bq_b; jb.bias[3] = bs_b;
    jb.o16[0] = K16; jb.o16[1] = V16; jb.o16[2] = Q16; jb.o16[3] = nullptr;
    jb.of[0] = nullptr; jb.of[1] = nullptr; jb.of[2] = nullptr; jb.of[3] = out_user;
    node_gemm8<<<gN4, blk512, 0, stream>>>(jb, N_NODES);
  }
  edge_gemm6<<<gE, blk512, 0, stream>>>(ei_b, t_b, lu_item, msg_b, W_t, b_t,
      WtT + 9 * 65536, pos + E_EDGES, e16);
  aggregate_fused4<<<gAgg, 128, 0, stream>>>(startb + (N_NODES + 1), esrc + E_EDGES,
      Q16, K16, V16, e16, out_user);
}